// Round 1
// baseline (347.029 us; speedup 1.0000x reference)
//
#include <hip/hip_runtime.h>
#include <hip/hip_bf16.h>

typedef __attribute__((ext_vector_type(8))) short short8;
typedef __attribute__((ext_vector_type(4))) float floatx4;

#define MFMA16(a, b, c) __builtin_amdgcn_mfma_f32_16x16x32_bf16((a), (b), (c), 0, 0, 0)

__device__ __forceinline__ short f2bf(float f) {
    union { float f; unsigned u; } x; x.f = f;
    unsigned r = (x.u + 0x7fffu + ((x.u >> 16) & 1u)) >> 16;
    return (short)r;
}
__device__ __forceinline__ float bf2f(short s) {
    union { float f; unsigned u; } x; x.u = ((unsigned)(unsigned short)s) << 16;
    return x.f;
}

// ---------------- weight transpose: W[c][o] fp32 -> Wt[o][c] bf16 ----------------
__global__ void transpose_w(const float* __restrict__ Wsrc, short* __restrict__ Wdst) {
    __shared__ float t[32][33];
    int o0 = blockIdx.x * 32, c0 = blockIdx.y * 32;
    int lx = threadIdx.x, ly = threadIdx.y;   // (32,8)
    for (int i = ly; i < 32; i += 8) t[i][lx] = Wsrc[(size_t)(c0 + i) * 512 + o0 + lx];
    __syncthreads();
    for (int i = ly; i < 32; i += 8) Wdst[(size_t)(o0 + i) * 512 + c0 + lx] = f2bf(t[lx][i]);
}

// ---------------- groupnorm: x[b][c][p] -> hnt[b][p][c] bf16 ----------------
__global__ __launch_bounds__(256) void groupnorm_k(const float* __restrict__ x,
                                                   short* __restrict__ hnt) {
    int b = blockIdx.x >> 5, g = blockIdx.x & 31;
    const float* xg = x + ((size_t)b * 512 + g * 16) * 1024;   // 16 rows x 1024
    float s = 0.f, ss = 0.f;
    for (int i = threadIdx.x; i < 16384; i += 256) {
        float v = xg[i]; s += v; ss += v * v;
    }
#pragma unroll
    for (int off = 32; off > 0; off >>= 1) {
        s  += __shfl_down(s,  off, 64);
        ss += __shfl_down(ss, off, 64);
    }
    __shared__ float red[8];
    int w = threadIdx.x >> 6;
    if ((threadIdx.x & 63) == 0) { red[w] = s; red[4 + w] = ss; }
    __syncthreads();
    float S  = red[0] + red[1] + red[2] + red[3];
    float SS = red[4] + red[5] + red[6] + red[7];
    float mean = S * (1.f / 16384.f);
    float var  = SS * (1.f / 16384.f) - mean * mean;
    float rstd = rsqrtf(var + 1e-5f);
    __shared__ __attribute__((aligned(16))) short tile[16 * 1026];  // pitch 1026 avoids bank conflicts
    for (int i = threadIdx.x; i < 16384; i += 256) {
        int c = i >> 10, p = i & 1023;
        tile[c * 1026 + p] = f2bf((xg[i] - mean) * rstd);
    }
    __syncthreads();
    for (int i = threadIdx.x; i < 16384; i += 256) {
        int p = i >> 4, c = i & 15;
        hnt[((size_t)b * 1024 + p) * 512 + g * 16 + c] = tile[c * 1026 + p];
    }
}

// ---------------- GEMM: Out[perm(m)][n] = sum_k A[m][k]*W[n][k] + bias[n] ----------------
// A: [1024][512] bf16 per batch, W: [512][512] bf16 (k-contiguous), Out bf16.
__global__ __launch_bounds__(256) void gemm_nt(const short* __restrict__ A, size_t a_bstride,
                                               const short* __restrict__ W,
                                               const float* __restrict__ bias,
                                               short* __restrict__ Out, size_t o_bstride,
                                               int permute) {
    const int tid = threadIdx.x;
    const int wv = tid >> 6, ln = tid & 63;
    const int m0 = blockIdx.x * 128, n0 = blockIdx.y * 128;
    const short* Ab = A + (size_t)blockIdx.z * a_bstride;
    short* Ob = Out + (size_t)blockIdx.z * o_bstride;

    __shared__ __attribute__((aligned(16))) short As[128 * 40];  // pitch 40 bf16 = 80B
    __shared__ __attribute__((aligned(16))) short Bs[128 * 40];

    floatx4 acc[4][4] = {};
    const int wm = (wv >> 1) * 64, wn = (wv & 1) * 64;
    const int fr = ln & 15, fq = ln >> 4;

    for (int kk = 0; kk < 512; kk += 32) {
        __syncthreads();
#pragma unroll
        for (int j = 0; j < 2; ++j) {
            int ch = j * 256 + tid;
            int r = ch >> 2, q = ch & 3;
            short8 va = *(const short8*)(Ab + (size_t)(m0 + r) * 512 + kk + q * 8);
            *(short8*)(As + r * 40 + q * 8) = va;
            short8 vb = *(const short8*)(W + (size_t)(n0 + r) * 512 + kk + q * 8);
            *(short8*)(Bs + r * 40 + q * 8) = vb;
        }
        __syncthreads();
        short8 af[4], bf[4];
#pragma unroll
        for (int t = 0; t < 4; ++t) {
            af[t] = *(const short8*)(As + (wm + t * 16 + fr) * 40 + fq * 8);
            bf[t] = *(const short8*)(Bs + (wn + t * 16 + fr) * 40 + fq * 8);
        }
#pragma unroll
        for (int mt = 0; mt < 4; ++mt)
#pragma unroll
            for (int nt = 0; nt < 4; ++nt)
                acc[mt][nt] = MFMA16(af[mt], bf[nt], acc[mt][nt]);
    }
#pragma unroll
    for (int mt = 0; mt < 4; ++mt) {
#pragma unroll
        for (int nt = 0; nt < 4; ++nt) {
            int n = n0 + wn + nt * 16 + fr;
            float bvv = bias ? bias[n] : 0.0f;
#pragma unroll
            for (int r = 0; r < 4; ++r) {
                int m = m0 + wm + mt * 16 + fq * 4 + r;
                int mrow = permute ? ((m & 31) * 32 + (m >> 5)) : m;
                Ob[(size_t)mrow * 512 + n] = f2bf(acc[mt][nt][r] + bvv);
            }
        }
    }
}

// ---------------- per-slice scores + softmax diagonal ----------------
// Qp/Kp layout: [b][x*32+y][c] bf16. One wave per slice (b,x1,x2).
__global__ __launch_bounds__(256) void attn_diag(const short* __restrict__ Qp,
                                                 const short* __restrict__ Kp,
                                                 float* __restrict__ Dm) {
    int tid = threadIdx.x, wv = tid >> 6, l = tid & 63;
    int slice = blockIdx.x * 4 + wv;
    int b = slice >> 10, x1 = (slice >> 5) & 31, x2 = slice & 31;
    const short* Qb = Qp + ((size_t)b * 1024 + x1 * 32) * 512;
    const short* Kb = Kp + ((size_t)b * 1024 + x2 * 32) * 512;
    int fr = l & 15, fq = l >> 4;
    floatx4 acc[2][2] = {};
    for (int kk = 0; kk < 512; kk += 32) {
        short8 a0 = *(const short8*)(Qb + (size_t)fr * 512 + kk + fq * 8);
        short8 a1 = *(const short8*)(Qb + (size_t)(16 + fr) * 512 + kk + fq * 8);
        short8 b0 = *(const short8*)(Kb + (size_t)fr * 512 + kk + fq * 8);
        short8 b1 = *(const short8*)(Kb + (size_t)(16 + fr) * 512 + kk + fq * 8);
        acc[0][0] = MFMA16(a0, b0, acc[0][0]);
        acc[0][1] = MFMA16(a0, b1, acc[0][1]);
        acc[1][0] = MFMA16(a1, b0, acc[1][0]);
        acc[1][1] = MFMA16(a1, b1, acc[1][1]);
    }
    const float scale = 0.04419417382415922f;  // 512^-0.5
    float v[16];
    float mx = -3.0e38f;
#pragma unroll
    for (int mt = 0; mt < 2; ++mt)
#pragma unroll
        for (int nt = 0; nt < 2; ++nt)
#pragma unroll
            for (int r = 0; r < 4; ++r) {
                float t = acc[mt][nt][r] * scale;
                v[(mt * 2 + nt) * 4 + r] = t;
                mx = fmaxf(mx, t);
            }
#pragma unroll
    for (int off = 32; off > 0; off >>= 1) mx = fmaxf(mx, __shfl_xor(mx, off, 64));
    float se = 0.f;
#pragma unroll
    for (int i = 0; i < 16; ++i) se += __expf(v[i] - mx);
#pragma unroll
    for (int off = 32; off > 0; off >>= 1) se += __shfl_xor(se, off, 64);
    // numerator at (y1=x1, y2=x2)
    int mt = x1 >> 4, nt = x2 >> 4, ri = x1 & 15;
    int src = ((ri >> 2) << 4) | (x2 & 15);
    int idx = (mt * 2 + nt) * 4 + (ri & 3);
    float cand = 0.f;
#pragma unroll
    for (int i = 0; i < 16; ++i) cand = (i == idx) ? v[i] : cand;
    float numer = __shfl(cand, src, 64);
    if (l == 0) Dm[slice] = __expf(numer - mx) / se;
}

// ---------------- epilogue: out[b][c][p] = x + D[b][p]*U[b][p][c] + bn[c] ----------------
__global__ __launch_bounds__(256) void epilogue_k(const float* __restrict__ x,
                                                  const short* __restrict__ U,
                                                  const float* __restrict__ Dm,
                                                  const float* __restrict__ bnb,
                                                  float* __restrict__ out) {
    const int tid = threadIdx.x;
    const int b = blockIdx.z, c0 = blockIdx.y * 64, p0 = blockIdx.x * 64;
    __shared__ __attribute__((aligned(16))) short t[64 * 72];
    __shared__ float dsh[64];
#pragma unroll
    for (int j = 0; j < 2; ++j) {
        int ch = j * 256 + tid, r = ch >> 3, q = ch & 7;
        short8 vv = *(const short8*)(U + ((size_t)b * 1024 + p0 + r) * 512 + c0 + q * 8);
        *(short8*)(t + r * 72 + q * 8) = vv;
    }
    if (tid < 64) dsh[tid] = Dm[b * 1024 + p0 + tid];
    __syncthreads();
    for (int e = tid; e < 4096; e += 256) {
        int ci = e >> 6, p = e & 63;
        size_t idx = ((size_t)b * 512 + c0 + ci) * 1024 + p0 + p;
        out[idx] = x[idx] + dsh[p] * bf2f(t[p * 72 + ci]) + bnb[c0 + ci];
    }
}

extern "C" void kernel_launch(void* const* d_in, const int* in_sizes, int n_in,
                              void* d_out, int out_size, void* d_ws, size_t ws_size,
                              hipStream_t stream) {
    const float* x  = (const float*)d_in[0];
    const float* Wq = (const float*)d_in[1];
    const float* bq = (const float*)d_in[2];
    const float* Wk = (const float*)d_in[3];
    const float* bk = (const float*)d_in[4];
    const float* Wv = (const float*)d_in[5];
    const float* bv = (const float*)d_in[6];
    const float* Wn = (const float*)d_in[7];
    const float* bn = (const float*)d_in[8];
    float* out = (float*)d_out;
    char* ws = (char*)d_ws;

    const size_t WSZ = 512 * 512 * 2;           // 524288 B per bf16 weight
    const size_t TSZ = (size_t)16 * 1024 * 512 * 2;  // 16.78 MB per bf16 tensor
    short* Wq_t = (short*)(ws);
    short* Wk_t = (short*)(ws + WSZ);
    short* Wv_t = (short*)(ws + 2 * WSZ);
    short* Wn_t = (short*)(ws + 3 * WSZ);
    short* hnt  = (short*)(ws + 4 * WSZ);            // reused as U after V-GEMM
    short* Qp   = (short*)(ws + 4 * WSZ + TSZ);
    short* Kp   = (short*)(ws + 4 * WSZ + 2 * TSZ);
    short* Vb   = (short*)(ws + 4 * WSZ + 3 * TSZ);
    float* Dm   = (float*)(ws + 4 * WSZ + 4 * TSZ);  // 16*1024 fp32
    short* U    = hnt;

    dim3 bt(32, 8);
    transpose_w<<<dim3(16, 16), bt, 0, stream>>>(Wq, Wq_t);
    transpose_w<<<dim3(16, 16), bt, 0, stream>>>(Wk, Wk_t);
    transpose_w<<<dim3(16, 16), bt, 0, stream>>>(Wv, Wv_t);
    transpose_w<<<dim3(16, 16), bt, 0, stream>>>(Wn, Wn_t);
    groupnorm_k<<<512, 256, 0, stream>>>(x, hnt);

    const size_t BS = 1024 * 512;  // per-batch stride in elements
    gemm_nt<<<dim3(8, 4, 16), 256, 0, stream>>>(hnt, BS, Wq_t, bq, Qp, BS, 1);
    gemm_nt<<<dim3(8, 4, 16), 256, 0, stream>>>(hnt, BS, Wk_t, bk, Kp, BS, 1);
    gemm_nt<<<dim3(8, 4, 16), 256, 0, stream>>>(hnt, BS, Wv_t, bv, Vb, BS, 0);
    attn_diag<<<4096, 256, 0, stream>>>(Qp, Kp, Dm);
    gemm_nt<<<dim3(8, 4, 16), 256, 0, stream>>>(Vb, BS, Wn_t, (const float*)nullptr, U, BS, 0);
    epilogue_k<<<dim3(16, 8, 16), 256, 0, stream>>>(x, U, Dm, bn, out);
}

// Round 2
// 242.012 us; speedup vs baseline: 1.4339x; 1.4339x over previous
//
#include <hip/hip_runtime.h>
#include <hip/hip_bf16.h>

typedef __attribute__((ext_vector_type(8))) short short8;
typedef __attribute__((ext_vector_type(4))) float floatx4;

#define MFMA16(a, b, c) __builtin_amdgcn_mfma_f32_16x16x32_bf16((a), (b), (c), 0, 0, 0)

__device__ __forceinline__ short f2bf(float f) {
    union { float f; unsigned u; } x; x.f = f;
    unsigned r = (x.u + 0x7fffu + ((x.u >> 16) & 1u)) >> 16;
    return (short)r;
}
__device__ __forceinline__ float bf2f(short s) {
    union { float f; unsigned u; } x; x.u = ((unsigned)(unsigned short)s) << 16;
    return x.f;
}

// async global->LDS, 16B per lane; LDS dest is wave-uniform base + lane*16
__device__ __forceinline__ void gl2lds16(const short* g, short* l) {
    void* gv = const_cast<short*>(g);
    __builtin_amdgcn_global_load_lds((__attribute__((address_space(1))) void*)gv,
                                     (__attribute__((address_space(3))) void*)l,
                                     16, 0, 0);
}

// ---------------- weight transpose: W[c][o] fp32 -> Wt[o][c] bf16 ----------------
__global__ void transpose_w(const float* __restrict__ Wsrc, short* __restrict__ Wdst) {
    __shared__ float t[32][33];
    int o0 = blockIdx.x * 32, c0 = blockIdx.y * 32;
    int lx = threadIdx.x, ly = threadIdx.y;   // (32,8)
    for (int i = ly; i < 32; i += 8) t[i][lx] = Wsrc[(size_t)(c0 + i) * 512 + o0 + lx];
    __syncthreads();
    for (int i = ly; i < 32; i += 8) Wdst[(size_t)(o0 + i) * 512 + c0 + lx] = f2bf(t[lx][i]);
}

// ---------------- groupnorm: x[b][c][p] -> hnt[b][p][c] bf16 ----------------
__global__ __launch_bounds__(256) void groupnorm_k(const float* __restrict__ x,
                                                   short* __restrict__ hnt) {
    int b = blockIdx.x >> 5, g = blockIdx.x & 31;
    const float* xg = x + ((size_t)b * 512 + g * 16) * 1024;   // 16 rows x 1024
    const float4* xg4 = (const float4*)xg;
    float s = 0.f, ss = 0.f;
    for (int i = threadIdx.x; i < 4096; i += 256) {
        float4 v = xg4[i];
        s  += v.x + v.y + v.z + v.w;
        ss += v.x * v.x + v.y * v.y + v.z * v.z + v.w * v.w;
    }
#pragma unroll
    for (int off = 32; off > 0; off >>= 1) {
        s  += __shfl_down(s,  off, 64);
        ss += __shfl_down(ss, off, 64);
    }
    __shared__ float red[8];
    int w = threadIdx.x >> 6;
    if ((threadIdx.x & 63) == 0) { red[w] = s; red[4 + w] = ss; }
    __syncthreads();
    float S  = red[0] + red[1] + red[2] + red[3];
    float SS = red[4] + red[5] + red[6] + red[7];
    float mean = S * (1.f / 16384.f);
    float var  = SS * (1.f / 16384.f) - mean * mean;
    float rstd = rsqrtf(var + 1e-5f);
    __shared__ __attribute__((aligned(16))) short tile[16 * 1026];  // pitch 1026 shorts
    for (int i = threadIdx.x; i < 4096; i += 256) {
        float4 v = xg4[i];
        int c = i >> 8, p = (i & 255) * 4;
        short* tp = tile + c * 1026 + p;
        tp[0] = f2bf((v.x - mean) * rstd);
        tp[1] = f2bf((v.y - mean) * rstd);
        tp[2] = f2bf((v.z - mean) * rstd);
        tp[3] = f2bf((v.w - mean) * rstd);
    }
    __syncthreads();
    for (int i = threadIdx.x; i < 2048; i += 256) {
        int p = i >> 1, half = i & 1;
        short8 v;
#pragma unroll
        for (int j = 0; j < 8; ++j) v[j] = tile[(half * 8 + j) * 1026 + p];
        *(short8*)(hnt + ((size_t)b * 1024 + p) * 512 + g * 16 + half * 8) = v;
    }
}

// ---------------- GEMM: Out[perm(m)][n] = sum_k A[m][k]*W[n][k] + bias[n] ----------------
// m97-style: global_load_lds width-16 staging, unpadded 128x32 LDS tiles,
// XOR chunk swizzle (q ^ ((r>>1)&3)) makes ds_read_b128 conflict-free.
__global__ __launch_bounds__(256) void gemm_nt(const short* __restrict__ A, size_t a_bstride,
                                               const short* __restrict__ W,
                                               const float* __restrict__ bias,
                                               short* __restrict__ Out, size_t o_bstride,
                                               int permute) {
    const int tid = threadIdx.x;
    const int wv = tid >> 6, ln = tid & 63;
    const int m0 = blockIdx.x * 128, n0 = blockIdx.y * 128;
    const short* Ab = A + (size_t)blockIdx.z * a_bstride;
    short* Ob = Out + (size_t)blockIdx.z * o_bstride;

    __shared__ __attribute__((aligned(16))) short As[128 * 32];
    __shared__ __attribute__((aligned(16))) short Bs[128 * 32];

    floatx4 acc[4][4] = {};
    const int wm = (wv >> 1) * 64, wn = (wv & 1) * 64;
    const int fr = ln & 15, fq = ln >> 4;

    for (int kk = 0; kk < 512; kk += 32) {
        __syncthreads();
#pragma unroll
        for (int j = 0; j < 2; ++j) {
            int s = (wv * 2 + j) * 64 + ln;       // 16B chunk slot in tile
            int r = s >> 2;
            int q = (s & 3) ^ ((r >> 1) & 3);     // swizzled logical chunk
            short* lbase = As + (size_t)(wv * 2 + j) * 512;   // wave-uniform
            gl2lds16(Ab + (size_t)(m0 + r) * 512 + kk + q * 8, lbase);
            short* lbaseB = Bs + (size_t)(wv * 2 + j) * 512;
            gl2lds16(W + (size_t)(n0 + r) * 512 + kk + q * 8, lbaseB);
        }
        __syncthreads();
        short8 af[4], bfr[4];
#pragma unroll
        for (int t = 0; t < 4; ++t) {
            int ra = wm + t * 16 + fr;
            af[t]  = *(const short8*)(As + ra * 32 + ((fq ^ ((ra >> 1) & 3)) * 8));
            int rb = wn + t * 16 + fr;
            bfr[t] = *(const short8*)(Bs + rb * 32 + ((fq ^ ((rb >> 1) & 3)) * 8));
        }
#pragma unroll
        for (int mt = 0; mt < 4; ++mt)
#pragma unroll
            for (int nt = 0; nt < 4; ++nt)
                acc[mt][nt] = MFMA16(af[mt], bfr[nt], acc[mt][nt]);
    }
#pragma unroll
    for (int mt = 0; mt < 4; ++mt) {
#pragma unroll
        for (int nt = 0; nt < 4; ++nt) {
            int n = n0 + wn + nt * 16 + fr;
            float bvv = bias ? bias[n] : 0.0f;
#pragma unroll
            for (int r = 0; r < 4; ++r) {
                int m = m0 + wm + mt * 16 + fq * 4 + r;
                int mrow = permute ? ((m & 31) * 32 + (m >> 5)) : m;
                Ob[(size_t)mrow * 512 + n] = f2bf(acc[mt][nt][r] + bvv);
            }
        }
    }
}

// ---------------- fused S-GEMM + per-32x32-block softmax diagonal ----------------
// S = Qp·Kp^T per batch (1024x1024x512). Each wave's 64x64 acc = 4 complete
// 32x32 slice-blocks (b, w, W); reduce each to exp(diag-max)/sumexp in-register.
__global__ __launch_bounds__(256) void attn_sm(const short* __restrict__ Qp,
                                               const short* __restrict__ Kp,
                                               float* __restrict__ Dm) {
    const int tid = threadIdx.x;
    const int wv = tid >> 6, ln = tid & 63;
    const int m0 = blockIdx.x * 128, n0 = blockIdx.y * 128, b = blockIdx.z;
    const short* Qb = Qp + (size_t)b * (1024 * 512);
    const short* Kb = Kp + (size_t)b * (1024 * 512);

    __shared__ __attribute__((aligned(16))) short As[128 * 32];
    __shared__ __attribute__((aligned(16))) short Bs[128 * 32];

    floatx4 acc[4][4] = {};
    const int wm = (wv >> 1) * 64, wn = (wv & 1) * 64;
    const int fr = ln & 15, fq = ln >> 4;

    for (int kk = 0; kk < 512; kk += 32) {
        __syncthreads();
#pragma unroll
        for (int j = 0; j < 2; ++j) {
            int s = (wv * 2 + j) * 64 + ln;
            int r = s >> 2;
            int q = (s & 3) ^ ((r >> 1) & 3);
            gl2lds16(Qb + (size_t)(m0 + r) * 512 + kk + q * 8, As + (size_t)(wv * 2 + j) * 512);
            gl2lds16(Kb + (size_t)(n0 + r) * 512 + kk + q * 8, Bs + (size_t)(wv * 2 + j) * 512);
        }
        __syncthreads();
        short8 af[4], bfr[4];
#pragma unroll
        for (int t = 0; t < 4; ++t) {
            int ra = wm + t * 16 + fr;
            af[t]  = *(const short8*)(As + ra * 32 + ((fq ^ ((ra >> 1) & 3)) * 8));
            int rb = wn + t * 16 + fr;
            bfr[t] = *(const short8*)(Bs + rb * 32 + ((fq ^ ((rb >> 1) & 3)) * 8));
        }
#pragma unroll
        for (int mt = 0; mt < 4; ++mt)
#pragma unroll
            for (int nt = 0; nt < 4; ++nt)
                acc[mt][nt] = MFMA16(af[mt], bfr[nt], acc[mt][nt]);
    }

    // ---- per-slice softmax-diagonal reduction (4 slices per wave) ----
    const float scale = 0.04419417382415922f;  // 512^-0.5
    const int wbase = (m0 + wm) >> 5;          // global slice row index base
    const int Wbase = (n0 + wn) >> 5;
#pragma unroll
    for (int si = 0; si < 2; ++si) {
#pragma unroll
        for (int sj = 0; sj < 2; ++sj) {
            int wg = wbase + si, Wg = Wbase + sj;
            float tv[16];
            float mx = -3.0e38f;
#pragma unroll
            for (int mi = 0; mi < 2; ++mi)
#pragma unroll
                for (int ni = 0; ni < 2; ++ni)
#pragma unroll
                    for (int r = 0; r < 4; ++r) {
                        float u = acc[2 * si + mi][2 * sj + ni][r] * scale;
                        tv[(mi * 2 + ni) * 4 + r] = u;
                        mx = fmaxf(mx, u);
                    }
#pragma unroll
            for (int off = 32; off > 0; off >>= 1) mx = fmaxf(mx, __shfl_xor(mx, off, 64));
            float se = 0.f;
#pragma unroll
            for (int i = 0; i < 16; ++i) se += __expf(tv[i] - mx);
#pragma unroll
            for (int off = 32; off > 0; off >>= 1) se += __shfl_xor(se, off, 64);
            // diagonal element lives at local (row = wg, col = Wg)
            if (fq == ((wg >> 2) & 3) && fr == (Wg & 15)) {
                int mi = wg >> 4, ni = Wg >> 4;
                float numer = tv[(mi * 2 + ni) * 4 + (wg & 3)];
                Dm[((size_t)b * 32 + wg) * 32 + Wg] = __expf(numer - mx) / se;
            }
        }
    }
}

// ---------------- epilogue: out[b][c][p] = x + D[b][p]*U[b][p][c] + bn[c] ----------------
__global__ __launch_bounds__(256) void epilogue_k(const float* __restrict__ x,
                                                  const short* __restrict__ U,
                                                  const float* __restrict__ Dm,
                                                  const float* __restrict__ bnb,
                                                  float* __restrict__ out) {
    const int tid = threadIdx.x;
    const int b = blockIdx.z, c0 = blockIdx.y * 64, p0 = blockIdx.x * 64;
    __shared__ __attribute__((aligned(16))) short t[64 * 72];
    __shared__ float dsh[64];
#pragma unroll
    for (int j = 0; j < 2; ++j) {
        int ch = j * 256 + tid, r = ch >> 3, q = ch & 7;
        short8 vv = *(const short8*)(U + ((size_t)b * 1024 + p0 + r) * 512 + c0 + q * 8);
        *(short8*)(t + r * 72 + q * 8) = vv;
    }
    if (tid < 64) dsh[tid] = Dm[b * 1024 + p0 + tid];
    __syncthreads();
    for (int e = tid; e < 4096; e += 256) {
        int ci = e >> 6, p = e & 63;
        size_t idx = ((size_t)b * 512 + c0 + ci) * 1024 + p0 + p;
        out[idx] = x[idx] + dsh[p] * bf2f(t[p * 72 + ci]) + bnb[c0 + ci];
    }
}

extern "C" void kernel_launch(void* const* d_in, const int* in_sizes, int n_in,
                              void* d_out, int out_size, void* d_ws, size_t ws_size,
                              hipStream_t stream) {
    const float* x  = (const float*)d_in[0];
    const float* Wq = (const float*)d_in[1];
    const float* bq = (const float*)d_in[2];
    const float* Wk = (const float*)d_in[3];
    const float* bk = (const float*)d_in[4];
    const float* Wv = (const float*)d_in[5];
    const float* bv = (const float*)d_in[6];
    const float* Wn = (const float*)d_in[7];
    const float* bn = (const float*)d_in[8];
    float* out = (float*)d_out;
    char* ws = (char*)d_ws;

    const size_t WSZ = 512 * 512 * 2;                // bf16 weight bytes
    const size_t TSZ = (size_t)16 * 1024 * 512 * 2;  // bf16 activation tensor bytes
    short* Wq_t = (short*)(ws);
    short* Wk_t = (short*)(ws + WSZ);
    short* Wv_t = (short*)(ws + 2 * WSZ);
    short* Wn_t = (short*)(ws + 3 * WSZ);
    short* hnt  = (short*)(ws + 4 * WSZ);            // reused as U after V-GEMM
    short* Qp   = (short*)(ws + 4 * WSZ + TSZ);
    short* Kp   = (short*)(ws + 4 * WSZ + 2 * TSZ);
    short* Vb   = (short*)(ws + 4 * WSZ + 3 * TSZ);
    float* Dm   = (float*)(ws + 4 * WSZ + 4 * TSZ);  // 16*1024 fp32
    short* U    = hnt;

    dim3 bt(32, 8);
    transpose_w<<<dim3(16, 16), bt, 0, stream>>>(Wq, Wq_t);
    transpose_w<<<dim3(16, 16), bt, 0, stream>>>(Wk, Wk_t);
    transpose_w<<<dim3(16, 16), bt, 0, stream>>>(Wv, Wv_t);
    transpose_w<<<dim3(16, 16), bt, 0, stream>>>(Wn, Wn_t);
    groupnorm_k<<<512, 256, 0, stream>>>(x, hnt);

    const size_t BS = 1024 * 512;  // per-batch stride in elements
    gemm_nt<<<dim3(8, 4, 16), 256, 0, stream>>>(hnt, BS, Wq_t, bq, Qp, BS, 1);
    gemm_nt<<<dim3(8, 4, 16), 256, 0, stream>>>(hnt, BS, Wk_t, bk, Kp, BS, 1);
    gemm_nt<<<dim3(8, 4, 16), 256, 0, stream>>>(hnt, BS, Wv_t, bv, Vb, BS, 0);
    attn_sm<<<dim3(8, 8, 16), 256, 0, stream>>>(Qp, Kp, Dm);
    gemm_nt<<<dim3(8, 4, 16), 256, 0, stream>>>(Vb, BS, Wn_t, (const float*)nullptr, U, BS, 0);
    epilogue_k<<<dim3(16, 8, 16), 256, 0, stream>>>(x, U, Dm, bn, out);
}

// Round 3
// 212.983 us; speedup vs baseline: 1.6294x; 1.1363x over previous
//
#include <hip/hip_runtime.h>
#include <hip/hip_bf16.h>

typedef __attribute__((ext_vector_type(8))) short short8;
typedef __attribute__((ext_vector_type(4))) float floatx4;

#define MFMA16(a, b, c) __builtin_amdgcn_mfma_f32_16x16x32_bf16((a), (b), (c), 0, 0, 0)

__device__ __forceinline__ short f2bf(float f) {
    union { float f; unsigned u; } x; x.f = f;
    unsigned r = (x.u + 0x7fffu + ((x.u >> 16) & 1u)) >> 16;
    return (short)r;
}

// async global->LDS, 16B per lane; LDS dest is wave-uniform base + lane*16
__device__ __forceinline__ void gl2lds16(const short* g, short* l) {
    void* gv = const_cast<short*>(g);
    __builtin_amdgcn_global_load_lds((__attribute__((address_space(1))) void*)gv,
                                     (__attribute__((address_space(3))) void*)l,
                                     16, 0, 0);
}

// ------------- weight prep: 4 transposes (fp32->bf16) + bias concat, one launch -------------
// z<3: W{q,k,v}[c][o] -> Wqkv_t[z*512+o][c];  z==3: Wn -> Wn_t[o][c]
__global__ void transpose_w4(const float* __restrict__ Wq, const float* __restrict__ Wk,
                             const float* __restrict__ Wv, const float* __restrict__ Wn,
                             const float* __restrict__ bq, const float* __restrict__ bk,
                             const float* __restrict__ bv,
                             short* __restrict__ Wqkv_t, short* __restrict__ Wn_t,
                             float* __restrict__ bias_cat) {
    __shared__ float t[32][33];
    int z = blockIdx.z;
    const float* Wsrc = (z == 0) ? Wq : (z == 1) ? Wk : (z == 2) ? Wv : Wn;
    int o0 = blockIdx.x * 32, c0 = blockIdx.y * 32;
    int lx = threadIdx.x, ly = threadIdx.y;   // (32,8)
    for (int i = ly; i < 32; i += 8) t[i][lx] = Wsrc[(size_t)(c0 + i) * 512 + o0 + lx];
    __syncthreads();
    for (int i = ly; i < 32; i += 8) {
        short v = f2bf(t[lx][i]);
        if (z < 3) Wqkv_t[(size_t)(z * 512 + o0 + i) * 512 + c0 + lx] = v;
        else       Wn_t[(size_t)(o0 + i) * 512 + c0 + lx] = v;
    }
    if (z < 3 && blockIdx.y == 0 && ly == 0) {
        const float* bsrc = (z == 0) ? bq : (z == 1) ? bk : bv;
        bias_cat[z * 512 + o0 + lx] = bsrc[o0 + lx];
    }
}

// ---------------- groupnorm: x[b][c][p] -> hnt[b][p][c] bf16 ----------------
__global__ __launch_bounds__(256) void groupnorm_k(const float* __restrict__ x,
                                                   short* __restrict__ hnt) {
    int b = blockIdx.x >> 5, g = blockIdx.x & 31;
    const float* xg = x + ((size_t)b * 512 + g * 16) * 1024;   // 16 rows x 1024
    const float4* xg4 = (const float4*)xg;
    float s = 0.f, ss = 0.f;
    for (int i = threadIdx.x; i < 4096; i += 256) {
        float4 v = xg4[i];
        s  += v.x + v.y + v.z + v.w;
        ss += v.x * v.x + v.y * v.y + v.z * v.z + v.w * v.w;
    }
#pragma unroll
    for (int off = 32; off > 0; off >>= 1) {
        s  += __shfl_down(s,  off, 64);
        ss += __shfl_down(ss, off, 64);
    }
    __shared__ float red[8];
    int w = threadIdx.x >> 6;
    if ((threadIdx.x & 63) == 0) { red[w] = s; red[4 + w] = ss; }
    __syncthreads();
    float S  = red[0] + red[1] + red[2] + red[3];
    float SS = red[4] + red[5] + red[6] + red[7];
    float mean = S * (1.f / 16384.f);
    float var  = SS * (1.f / 16384.f) - mean * mean;
    float rstd = rsqrtf(var + 1e-5f);
    __shared__ __attribute__((aligned(16))) short tile[16 * 1026];
    for (int i = threadIdx.x; i < 4096; i += 256) {
        float4 v = xg4[i];
        int c = i >> 8, p = (i & 255) * 4;
        short* tp = tile + c * 1026 + p;
        tp[0] = f2bf((v.x - mean) * rstd);
        tp[1] = f2bf((v.y - mean) * rstd);
        tp[2] = f2bf((v.z - mean) * rstd);
        tp[3] = f2bf((v.w - mean) * rstd);
    }
    __syncthreads();
    for (int i = threadIdx.x; i < 2048; i += 256) {
        int p = i >> 1, half = i & 1;
        short8 v;
#pragma unroll
        for (int j = 0; j < 8; ++j) v[j] = tile[(half * 8 + j) * 1026 + p];
        *(short8*)(hnt + ((size_t)b * 1024 + p) * 512 + g * 16 + half * 8) = v;
    }
}

// ---------------- fused QKV GEMM: N=1536 over concat weights ----------------
// n<512 -> Qp (spatially permuted rows), n<1024 -> Kp (permuted), else Vb.
__global__ __launch_bounds__(256) void qkv_gemm(const short* __restrict__ A,
                                                const short* __restrict__ Wt,
                                                const float* __restrict__ bias_cat,
                                                short* __restrict__ Qp,
                                                short* __restrict__ Kp,
                                                short* __restrict__ Vb) {
    const int tid = threadIdx.x;
    const int wv = tid >> 6, ln = tid & 63;
    const int m0 = blockIdx.x * 128, n0 = blockIdx.y * 128;
    const size_t BS = 1024 * 512;
    const short* Ab = A + (size_t)blockIdx.z * BS;
    const int tsel = n0 >> 9;
    const int permute = (tsel < 2);
    short* Ob = ((tsel == 0) ? Qp : (tsel == 1) ? Kp : Vb) + (size_t)blockIdx.z * BS;

    __shared__ __attribute__((aligned(16))) short As[128 * 32];
    __shared__ __attribute__((aligned(16))) short Bs[128 * 32];

    floatx4 acc[4][4] = {};
    const int wm = (wv >> 1) * 64, wn = (wv & 1) * 64;
    const int fr = ln & 15, fq = ln >> 4;

    for (int kk = 0; kk < 512; kk += 32) {
        __syncthreads();
#pragma unroll
        for (int j = 0; j < 2; ++j) {
            int s = (wv * 2 + j) * 64 + ln;
            int r = s >> 2;
            int q = (s & 3) ^ ((r >> 1) & 3);
            gl2lds16(Ab + (size_t)(m0 + r) * 512 + kk + q * 8, As + (size_t)(wv * 2 + j) * 512);
            gl2lds16(Wt + (size_t)(n0 + r) * 512 + kk + q * 8, Bs + (size_t)(wv * 2 + j) * 512);
        }
        __syncthreads();
        short8 af[4], bfr[4];
#pragma unroll
        for (int t = 0; t < 4; ++t) {
            int ra = wm + t * 16 + fr;
            af[t]  = *(const short8*)(As + ra * 32 + ((fq ^ ((ra >> 1) & 3)) * 8));
            int rb = wn + t * 16 + fr;
            bfr[t] = *(const short8*)(Bs + rb * 32 + ((fq ^ ((rb >> 1) & 3)) * 8));
        }
#pragma unroll
        for (int mt = 0; mt < 4; ++mt)
#pragma unroll
            for (int nt = 0; nt < 4; ++nt)
                acc[mt][nt] = MFMA16(af[mt], bfr[nt], acc[mt][nt]);
    }
#pragma unroll
    for (int mt = 0; mt < 4; ++mt) {
#pragma unroll
        for (int nt = 0; nt < 4; ++nt) {
            int n = n0 + wn + nt * 16 + fr;
            float bvv = bias_cat[n];
            int nn = n & 511;
#pragma unroll
            for (int r = 0; r < 4; ++r) {
                int m = m0 + wm + mt * 16 + fq * 4 + r;
                int mrow = permute ? ((m & 31) * 32 + (m >> 5)) : m;
                Ob[(size_t)mrow * 512 + nn] = f2bf(acc[mt][nt][r] + bvv);
            }
        }
    }
}

// ---------------- fused S-GEMM + per-32x32-block softmax diagonal, 128x256 tiles ----------------
__global__ __launch_bounds__(256, 2) void attn_sm(const short* __restrict__ Qp,
                                                  const short* __restrict__ Kp,
                                                  float* __restrict__ Dm) {
    const int tid = threadIdx.x;
    const int wv = tid >> 6, ln = tid & 63;
    const int m0 = blockIdx.x * 128, n0 = blockIdx.y * 256, b = blockIdx.z;
    const short* Qb = Qp + (size_t)b * (1024 * 512);
    const short* Kb = Kp + (size_t)b * (1024 * 512);

    __shared__ __attribute__((aligned(16))) short As[128 * 32];
    __shared__ __attribute__((aligned(16))) short Bs[256 * 32];

    floatx4 acc[4][8] = {};
    const int wm = (wv >> 1) * 64, wn = (wv & 1) * 128;
    const int fr = ln & 15, fq = ln >> 4;

    for (int kk = 0; kk < 512; kk += 32) {
        __syncthreads();
#pragma unroll
        for (int j = 0; j < 2; ++j) {
            int s = (wv * 2 + j) * 64 + ln;
            int r = s >> 2;
            int q = (s & 3) ^ ((r >> 1) & 3);
            gl2lds16(Qb + (size_t)(m0 + r) * 512 + kk + q * 8, As + (size_t)(wv * 2 + j) * 512);
        }
#pragma unroll
        for (int j = 0; j < 4; ++j) {
            int s = (wv * 4 + j) * 64 + ln;
            int r = s >> 2;
            int q = (s & 3) ^ ((r >> 1) & 3);
            gl2lds16(Kb + (size_t)(n0 + r) * 512 + kk + q * 8, Bs + (size_t)(wv * 4 + j) * 512);
        }
        __syncthreads();
        short8 af[4], bfr[8];
#pragma unroll
        for (int t = 0; t < 4; ++t) {
            int ra = wm + t * 16 + fr;
            af[t] = *(const short8*)(As + ra * 32 + ((fq ^ ((ra >> 1) & 3)) * 8));
        }
#pragma unroll
        for (int u = 0; u < 8; ++u) {
            int rb = wn + u * 16 + fr;
            bfr[u] = *(const short8*)(Bs + rb * 32 + ((fq ^ ((rb >> 1) & 3)) * 8));
        }
#pragma unroll
        for (int mt = 0; mt < 4; ++mt)
#pragma unroll
            for (int nt = 0; nt < 8; ++nt)
                acc[mt][nt] = MFMA16(af[mt], bfr[nt], acc[mt][nt]);
    }

    // ---- per-slice softmax-diagonal (2x4 = 8 slices per wave) ----
    const float scale = 0.04419417382415922f;  // 512^-0.5
    const int wbase = (m0 + wm) >> 5;
    const int Wbase = (n0 + wn) >> 5;
#pragma unroll
    for (int si = 0; si < 2; ++si) {
#pragma unroll
        for (int sj = 0; sj < 4; ++sj) {
            int wg = wbase + si, Wg = Wbase + sj;
            float tv[16];
            float mx = -3.0e38f;
#pragma unroll
            for (int mi = 0; mi < 2; ++mi)
#pragma unroll
                for (int ni = 0; ni < 2; ++ni)
#pragma unroll
                    for (int r = 0; r < 4; ++r) {
                        float u = acc[2 * si + mi][2 * sj + ni][r] * scale;
                        tv[(mi * 2 + ni) * 4 + r] = u;
                        mx = fmaxf(mx, u);
                    }
#pragma unroll
            for (int off = 32; off > 0; off >>= 1) mx = fmaxf(mx, __shfl_xor(mx, off, 64));
            float se = 0.f;
#pragma unroll
            for (int i = 0; i < 16; ++i) se += __expf(tv[i] - mx);
#pragma unroll
            for (int off = 32; off > 0; off >>= 1) se += __shfl_xor(se, off, 64);
            if (fq == ((wg >> 2) & 3) && fr == (Wg & 15)) {
                int mi = wg >> 4, ni = Wg >> 4;
                float numer = tv[(mi * 2 + ni) * 4 + (wg & 3)];
                Dm[((size_t)b * 32 + wg) * 32 + Wg] = __expf(numer - mx) / se;
            }
        }
    }
}

// ---------------- fused out-GEMM: out[b][n][m] = x + D[b][m]*(V·Wn)[m][n] + bn[n] ----------------
__global__ __launch_bounds__(256) void out_gemm(const short* __restrict__ A,
                                                const short* __restrict__ Wt,
                                                const float* __restrict__ Dm,
                                                const float* __restrict__ bnb,
                                                const float* __restrict__ x,
                                                float* __restrict__ out) {
    const int tid = threadIdx.x;
    const int wv = tid >> 6, ln = tid & 63;
    const int m0 = blockIdx.x * 128, n0 = blockIdx.y * 128, b = blockIdx.z;
    const size_t BS = 1024 * 512;
    const short* Ab = A + (size_t)b * BS;

    __shared__ __attribute__((aligned(16))) short As[128 * 32];
    __shared__ __attribute__((aligned(16))) short Bs[128 * 32];

    floatx4 acc[4][4] = {};
    const int wm = (wv >> 1) * 64, wn = (wv & 1) * 64;
    const int fr = ln & 15, fq = ln >> 4;

    for (int kk = 0; kk < 512; kk += 32) {
        __syncthreads();
#pragma unroll
        for (int j = 0; j < 2; ++j) {
            int s = (wv * 2 + j) * 64 + ln;
            int r = s >> 2;
            int q = (s & 3) ^ ((r >> 1) & 3);
            gl2lds16(Ab + (size_t)(m0 + r) * 512 + kk + q * 8, As + (size_t)(wv * 2 + j) * 512);
            gl2lds16(Wt + (size_t)(n0 + r) * 512 + kk + q * 8, Bs + (size_t)(wv * 2 + j) * 512);
        }
        __syncthreads();
        short8 af[4], bfr[4];
#pragma unroll
        for (int t = 0; t < 4; ++t) {
            int ra = wm + t * 16 + fr;
            af[t]  = *(const short8*)(As + ra * 32 + ((fq ^ ((ra >> 1) & 3)) * 8));
            int rb = wn + t * 16 + fr;
            bfr[t] = *(const short8*)(Bs + rb * 32 + ((fq ^ ((rb >> 1) & 3)) * 8));
        }
#pragma unroll
        for (int mt = 0; mt < 4; ++mt)
#pragma unroll
            for (int nt = 0; nt < 4; ++nt)
                acc[mt][nt] = MFMA16(af[mt], bfr[nt], acc[mt][nt]);
    }
#pragma unroll
    for (int mt = 0; mt < 4; ++mt) {
        int mbase = m0 + wm + mt * 16 + fq * 4;
        float4 d4 = *(const float4*)(Dm + (size_t)b * 1024 + mbase);
#pragma unroll
        for (int nt = 0; nt < 4; ++nt) {
            int n = n0 + wn + nt * 16 + fr;
            float bvv = bnb[n];
            size_t base = ((size_t)b * 512 + n) * 1024 + mbase;
            float4 x4 = *(const float4*)(x + base);
            float4 o;
            o.x = x4.x + d4.x * acc[mt][nt][0] + bvv;
            o.y = x4.y + d4.y * acc[mt][nt][1] + bvv;
            o.z = x4.z + d4.z * acc[mt][nt][2] + bvv;
            o.w = x4.w + d4.w * acc[mt][nt][3] + bvv;
            *(float4*)(out + base) = o;
        }
    }
}

extern "C" void kernel_launch(void* const* d_in, const int* in_sizes, int n_in,
                              void* d_out, int out_size, void* d_ws, size_t ws_size,
                              hipStream_t stream) {
    const float* x  = (const float*)d_in[0];
    const float* Wq = (const float*)d_in[1];
    const float* bq = (const float*)d_in[2];
    const float* Wk = (const float*)d_in[3];
    const float* bk = (const float*)d_in[4];
    const float* Wv = (const float*)d_in[5];
    const float* bv = (const float*)d_in[6];
    const float* Wn = (const float*)d_in[7];
    const float* bn = (const float*)d_in[8];
    float* out = (float*)d_out;
    char* ws = (char*)d_ws;

    const size_t WQKV = (size_t)1536 * 512 * 2;       // 1.57 MB
    const size_t WSZ  = (size_t)512 * 512 * 2;        // 0.52 MB
    const size_t BIAS = 1536 * sizeof(float);
    const size_t TSZ  = (size_t)16 * 1024 * 512 * 2;  // 16.78 MB
    short* Wqkv_t   = (short*)(ws);
    short* Wn_t     = (short*)(ws + WQKV);
    float* bias_cat = (float*)(ws + WQKV + WSZ);
    char*  base     = ws + WQKV + WSZ + BIAS;
    short* hnt = (short*)(base);
    short* Qp  = (short*)(base + TSZ);
    short* Kp  = (short*)(base + 2 * TSZ);
    short* Vb  = (short*)(base + 3 * TSZ);
    float* Dm  = (float*)(base + 4 * TSZ);            // 16*1024 fp32

    transpose_w4<<<dim3(16, 16, 4), dim3(32, 8), 0, stream>>>(
        Wq, Wk, Wv, Wn, bq, bk, bv, Wqkv_t, Wn_t, bias_cat);
    groupnorm_k<<<512, 256, 0, stream>>>(x, hnt);
    qkv_gemm<<<dim3(8, 12, 16), 256, 0, stream>>>(hnt, Wqkv_t, bias_cat, Qp, Kp, Vb);
    attn_sm<<<dim3(8, 4, 16), 256, 0, stream>>>(Qp, Kp, Dm);
    out_gemm<<<dim3(8, 4, 16), 256, 0, stream>>>(Vb, Wn_t, Dm, bn, x, out);
}